// Round 1
// 303.411 us; speedup vs baseline: 1.0346x; 1.0346x over previous
//
#include <hip/hip_runtime.h>
#include <math.h>

#define CCH 230
#define REL 53
#define BAG 1024
#define SLEN 128
#define LOUT 126

typedef __bf16 bf16x8 __attribute__((ext_vector_type(8)));
typedef float f32x4 __attribute__((ext_vector_type(4)));

// ---- workspace layout ----
// ushort region: B fragments [ntile(16)][ks(6)][lane(64)][j(8)] = 49152 ushorts
#define WS_BF_USHORTS (16 * 6 * 64 * 8)
#define WS_BSUM 24576     // float offset: 256 bias sums
#define WS_V    24832     // float offset: 256 = attW @ MR[:,rel]
#define WS_SCORES 25088   // float offset: 1024 scores

__device__ __forceinline__ unsigned short f2bf(float f) {
    unsigned u = __builtin_bit_cast(unsigned, f);
    unsigned r = (u + 0x7fffu + ((u >> 16) & 1u)) >> 16;
    return (unsigned short)r;
}

// ---------------- prep (B fragment pack + bias) fused with attv ----------------
__global__ void pa_kernel(const float* __restrict__ Wv, const float* __restrict__ Wp1,
                          const float* __restrict__ Wp2, const float* __restrict__ bv,
                          const float* __restrict__ bp1, const float* __restrict__ bp2,
                          const float* __restrict__ attW, const float* __restrict__ MR,
                          const int* __restrict__ relp, float* __restrict__ ws,
                          float* __restrict__ att_out) {
    if (blockIdx.x < 193) {
        int idx = blockIdx.x * 256 + threadIdx.x;
        if (idx < WS_BF_USHORTS) {
            int j = idx & 7;
            int lane = (idx >> 3) & 63;
            int q = idx >> 9;
            int ks = q % 6, ntile = q / 6;
            int n = ntile * 16 + (lane & 15);
            int k = ks * 32 + (lane >> 4) * 8 + j;
            float v = 0.f;
            if (k < 180 && n < CCH) {
                int jw = k / 60;
                int d = k - jw * 60;
                if (d < 50)      v = Wv[(jw * 50 + d) * CCH + n];
                else if (d < 55) v = Wp1[(jw * 5 + (d - 50)) * CCH + n];
                else             v = Wp2[(jw * 5 + (d - 55)) * CCH + n];
            }
            ((unsigned short*)ws)[idx] = f2bf(v);
        } else {
            int ch = idx - WS_BF_USHORTS;
            float v = 0.f;
            if (ch < CCH) { v = bv[ch] + bp1[ch] + bp2[ch]; att_out[ch] = 0.f; }
            ws[WS_BSUM + ch] = v;
        }
    } else {
        int i = (blockIdx.x - 193) * 4 + (threadIdx.x >> 6);
        int lane = threadIdx.x & 63;
        if (i < CCH) {
            int rel = *relp;
            float s = 0.f;
            for (int j = lane; j < CCH; j += 64) s += attW[i * CCH + j] * MR[j * REL + rel];
            for (int off = 32; off > 0; off >>= 1) s += __shfl_down(s, off, 64);
            if (lane == 0) ws[WS_V + i] = s;
        }
    }
}

// ---------------- fused gather + MFMA GEMM, 512 threads, B-frags hoisted ----------------
__global__ __launch_bounds__(512, 4) void conv_kernel(
    const int* __restrict__ sen, const int* __restrict__ p1, const int* __restrict__ p2,
    const float* __restrict__ wordVec, const float* __restrict__ posVec1,
    const float* __restrict__ posVec2, const float* __restrict__ ws,
    const float* __restrict__ MRb, const int* __restrict__ relp,
    float* __restrict__ cnn_out, float* __restrict__ scores) {
    // x[l][d] bf16, row stride EXACTLY 60: im2col row m contiguous at m*60+k
    __shared__ __align__(16) unsigned short x_lds[132 * 60];
    __shared__ float s_red[8];
    const int b = blockIdx.x;
    const int tid = threadIdx.x;
    const int lane = tid & 63, w = tid >> 6;
    const int quad = lane >> 4, l16 = lane & 15;
    const unsigned short* wsu = (const unsigned short*)ws;

    // hoist ALL B-fragment loads (LDS-independent): latency hides behind gather
    bf16x8 bfrag[6][2];
    #pragma unroll
    for (int ks = 0; ks < 6; ++ks)
        #pragma unroll
        for (int nt = 0; nt < 2; ++nt) {
            int ntile = w * 2 + nt;
            bfrag[ks][nt] = *reinterpret_cast<const bf16x8*>(wsu + ((ntile * 6 + ks) * 64 + lane) * 8);
        }

    // gather: one slot per thread (512 slots = 128 rows x 4); indices loaded
    // directly (4 lanes share one sen address -> broadcast), no LDS stage/barrier
    {
        int l = tid >> 2, t = tid & 3;
        int si = sen[b * SLEN + l];
        if (t < 3) {
            float v[16];
            const float* base = wordVec + si * 50 + t * 16;
            #pragma unroll
            for (int k2 = 0; k2 < 8; ++k2) {
                float2 f = *reinterpret_cast<const float2*>(base + 2 * k2);
                v[2 * k2] = f.x; v[2 * k2 + 1] = f.y;
            }
            ushort4* dst = reinterpret_cast<ushort4*>(x_lds + l * 60 + t * 16);
            #pragma unroll
            for (int q = 0; q < 4; ++q) {
                ushort4 o;
                o.x = f2bf(v[4 * q + 0]); o.y = f2bf(v[4 * q + 1]);
                o.z = f2bf(v[4 * q + 2]); o.w = f2bf(v[4 * q + 3]);
                dst[q] = o;
            }
        } else {
            float v[12];
            float2 wv = *reinterpret_cast<const float2*>(wordVec + si * 50 + 48);
            v[0] = wv.x; v[1] = wv.y;
            int i1 = p1[b * SLEN + l] * 5, i2 = p2[b * SLEN + l] * 5;
            #pragma unroll
            for (int j = 0; j < 5; ++j) { v[2 + j] = posVec1[i1 + j]; v[7 + j] = posVec2[i2 + j]; }
            ushort4* dst = reinterpret_cast<ushort4*>(x_lds + l * 60 + 48);
            #pragma unroll
            for (int q = 0; q < 3; ++q) {
                ushort4 o;
                o.x = f2bf(v[4 * q + 0]); o.y = f2bf(v[4 * q + 1]);
                o.z = f2bf(v[4 * q + 2]); o.w = f2bf(v[4 * q + 3]);
                dst[q] = o;
            }
        }
    }
    // zero pad rows 128..131 (read via im2col for m=126..129 and the k-pad)
    if (tid < 16) {
        int l = SLEN + (tid >> 2), t = tid & 3;
        ushort4 z; z.x = z.y = z.z = z.w = 0;
        ushort4* dst = reinterpret_cast<ushort4*>(x_lds + l * 60 + ((t < 3) ? t * 16 : 48));
        if (t < 3) { dst[0] = z; dst[1] = z; dst[2] = z; dst[3] = z; }
        else       { dst[0] = z; dst[1] = z; dst[2] = z; }
    }
    __syncthreads();

    f32x4 acc[8][2];
    #pragma unroll
    for (int mt = 0; mt < 8; ++mt)
        #pragma unroll
        for (int nt = 0; nt < 2; ++nt) acc[mt][nt] = (f32x4){0.f, 0.f, 0.f, 0.f};

    union AU { uint2 u2[2]; bf16x8 v; };

    #pragma unroll
    for (int ks = 0; ks < 6; ++ks) {
        int kg = ks * 4 + quad;          // k = kg*8 + j
        #pragma unroll
        for (int mt = 0; mt < 8; ++mt) {
            int m = mt * 16 + l16;
            const uint2* ap = reinterpret_cast<const uint2*>(x_lds + m * 60 + kg * 8);
            AU a; a.u2[0] = ap[0]; a.u2[1] = ap[1];
            #pragma unroll
            for (int nt = 0; nt < 2; ++nt)
                acc[mt][nt] = __builtin_amdgcn_mfma_f32_16x16x32_bf16(a.v, bfrag[ks][nt], acc[mt][nt], 0, 0, 0);
        }
    }

    // epilogue: masked max over l, cross-quad reduce, bias+tanh, store, fused score
    float vals[2];
    #pragma unroll
    for (int nt = 0; nt < 2; ++nt) {
        float mv = -3.0e38f;
        #pragma unroll
        for (int mt = 0; mt < 8; ++mt) {
            #pragma unroll
            for (int r = 0; r < 4; ++r) {
                int l = mt * 16 + quad * 4 + r;
                if (l < LOUT) mv = fmaxf(mv, acc[mt][nt][r]);
            }
        }
        mv = fmaxf(mv, __shfl_xor(mv, 16, 64));
        mv = fmaxf(mv, __shfl_xor(mv, 32, 64));
        int ch = w * 32 + nt * 16 + l16;
        float t = tanhf(mv + ws[WS_BSUM + ch]);
        vals[nt] = t;
        if (quad == 0 && ch < CCH) cnn_out[b * CCH + ch] = t;
    }

    float s = 0.f;
    if (quad == 0) {
        #pragma unroll
        for (int nt = 0; nt < 2; ++nt) {
            int ch = w * 32 + nt * 16 + l16;
            if (ch < CCH) s += vals[nt] * ws[WS_V + ch];
        }
    }
    for (int off = 32; off > 0; off >>= 1) s += __shfl_down(s, off, 64);
    if (lane == 0) s_red[w] = s;
    __syncthreads();
    if (tid == 0) {
        float t = MRb[*relp];
        #pragma unroll
        for (int i = 0; i < 8; ++i) t += s_red[i];
        scores[b] = t;
    }
}

// ---------------- bag softmax + weighted partial sums (32 blocks) ----------------
__global__ void final1_kernel(const float* __restrict__ cnn, const float* __restrict__ scores,
                              float* __restrict__ att_out, float* __restrict__ w_out) {
    __shared__ float redm[4], reds[4];
    __shared__ float wloc[32];
    int tid = threadIdx.x, g = blockIdx.x;
    // redundant (per-block) global softmax over the 1024 scores: 4 KB, L2-hit
    float s0[4];
    float mx = -3.0e38f;
    #pragma unroll
    for (int k = 0; k < 4; ++k) { s0[k] = scores[tid + 256 * k]; mx = fmaxf(mx, s0[k]); }
    #pragma unroll
    for (int off = 32; off > 0; off >>= 1) mx = fmaxf(mx, __shfl_xor(mx, off, 64));
    if ((tid & 63) == 0) redm[tid >> 6] = mx;
    __syncthreads();
    mx = fmaxf(fmaxf(redm[0], redm[1]), fmaxf(redm[2], redm[3]));
    float sum = 0.f;
    #pragma unroll
    for (int k = 0; k < 4; ++k) sum += expf(s0[k] - mx);
    #pragma unroll
    for (int off = 32; off > 0; off >>= 1) sum += __shfl_xor(sum, off, 64);
    if ((tid & 63) == 0) reds[tid >> 6] = sum;
    __syncthreads();
    sum = reds[0] + reds[1] + reds[2] + reds[3];

    int b0 = g * 32;
    if (tid < 32) {
        float w = expf(scores[b0 + tid] - mx) / sum;
        wloc[tid] = w;
        w_out[b0 + tid] = w;
    }
    __syncthreads();
    // partial weighted sum over this block's 32 bags; coalesced cnn reads
    if (tid < CCH) {
        float a = 0.f;
        #pragma unroll 8
        for (int bb = 0; bb < 32; ++bb) a += wloc[bb] * cnn[(b0 + bb) * CCH + tid];
        atomicAdd(&att_out[tid], a);
    }
}

// ---------------- final logits + softmax (tiny) ----------------
__global__ void final2_kernel(const float* __restrict__ att_in, const float* __restrict__ MR,
                              const float* __restrict__ MRb, float* __restrict__ out0) {
    __shared__ float MRs[CCH * REL];
    __shared__ float atts[CCH];
    __shared__ float lbuf[64];
    int tid = threadIdx.x;  // 256
    for (int i = tid; i < CCH * REL; i += 256) MRs[i] = MR[i];
    if (tid < CCH) atts[tid] = att_in[tid];
    __syncthreads();
    float t = 0.f;
    if (tid < REL) {
        t = MRb[tid];
        #pragma unroll 10
        for (int c = 0; c < CCH; ++c) t += atts[c] * MRs[c * REL + tid];
        lbuf[tid] = t;
    }
    __syncthreads();
    if (tid == 0) {
        float m2 = -3.0e38f;
        for (int i = 0; i < REL; ++i) m2 = fmaxf(m2, lbuf[i]);
        float s2 = 0.f;
        for (int i = 0; i < REL; ++i) s2 += expf(lbuf[i] - m2);
        lbuf[60] = m2; lbuf[61] = s2;
    }
    __syncthreads();
    if (tid < REL) out0[tid] = expf(t - lbuf[60]) / lbuf[61];
}

extern "C" void kernel_launch(void* const* d_in, const int* in_sizes, int n_in,
                              void* d_out, int out_size, void* d_ws, size_t ws_size,
                              hipStream_t stream) {
    const int* sen = (const int*)d_in[0];
    const int* p1  = (const int*)d_in[1];
    const int* p2  = (const int*)d_in[2];
    const float* wordVec = (const float*)d_in[3];
    const float* posVec1 = (const float*)d_in[4];
    const float* posVec2 = (const float*)d_in[5];
    const float* Wv  = (const float*)d_in[6];
    const float* Wp1 = (const float*)d_in[7];
    const float* Wp2 = (const float*)d_in[8];
    const float* bv  = (const float*)d_in[9];
    const float* bp1 = (const float*)d_in[10];
    const float* bp2 = (const float*)d_in[11];
    const float* attW = (const float*)d_in[12];
    const float* MR  = (const float*)d_in[13];
    const float* MRb = (const float*)d_in[14];
    const int* relp  = (const int*)d_in[15];

    float* ws = (float*)d_ws;
    float* out = (float*)d_out;
    float* out0    = out;
    float* att_out = out + REL;
    float* cnn_out = out + REL + CCH;
    float* w_out   = out + REL + CCH + BAG * CCH;

    hipLaunchKernelGGL(pa_kernel, dim3(193 + 58), dim3(256), 0, stream,
                       Wv, Wp1, Wp2, bv, bp1, bp2, attW, MR, relp, ws, att_out);
    hipLaunchKernelGGL(conv_kernel, dim3(BAG), dim3(512), 0, stream,
                       sen, p1, p2, wordVec, posVec1, posVec2, ws, MRb, relp,
                       cnn_out, ws + WS_SCORES);
    hipLaunchKernelGGL(final1_kernel, dim3(32), dim3(256), 0, stream,
                       cnn_out, ws + WS_SCORES, att_out, w_out);
    hipLaunchKernelGGL(final2_kernel, dim3(1), dim3(256), 0, stream,
                       att_out, MR, MRb, out0);
}